// Round 6
// baseline (137.556 us; speedup 1.0000x reference)
//
#include <hip/hip_runtime.h>
#include <hip/hip_bf16.h>
#include <math.h>

#define S_LEN 4096
#define NH    8

typedef __attribute__((ext_vector_type(8))) short bf16x8;
typedef __attribute__((ext_vector_type(4))) short bf16x4;
typedef __attribute__((ext_vector_type(4))) float f32x4;
typedef __attribute__((ext_vector_type(16))) float f32x16;

#define QSCALE 0.18033688011112042f   // 0.125 * log2(e): scores land in exp2 domain

// fp32 -> bf16 round-to-nearest-even (scalar)
__device__ __forceinline__ short f2bf(float f) {
    union { float f; unsigned u; } v; v.f = f;
    unsigned r = v.u + 0x7fffu + ((v.u >> 16) & 1u);
    return (short)(r >> 16);
}

// packed 2x fp32 -> bf16 (v_cvt_pk_bf16_f32 on gfx950)
__device__ __forceinline__ int pk2(float a, float b) {
    __hip_bfloat162 t = __float22bfloat162_rn(make_float2(a, b));
    union { __hip_bfloat162 h; int i; } u; u.h = t;
    return u.i;
}

// async 16B global->LDS; HW writes lane i's 16B to ldsbase + i*16
__device__ __forceinline__ void gload16(const void* g, void* l) {
    __builtin_amdgcn_global_load_lds(
        (const __attribute__((address_space(1))) unsigned*)g,
        (__attribute__((address_space(3))) unsigned*)l, 16, 0, 0);
}

// ---------------------------------------------------------------------------
// Stage a 64x64 bf16 tile into an 8KB LDS tile with XOR-swizzled 16B column
// groups: phys(row, cg) = row*128B + ((cg ^ (row&7)) * 16B). Swizzle applied
// on the GLOBAL source address so wave-uniform-base global_load_lds lands
// data where frag() expects.
// ---------------------------------------------------------------------------
__device__ __forceinline__ void stage_tile(const short* gsrc, size_t gstride,
                                           short* tile, int t)
{
    const int wave = t >> 6, lane = t & 63;
    const int sub = lane >> 3;
    const int cg  = (lane & 7) ^ sub;
#pragma unroll
    for (int j = 0; j < 2; ++j) {
        const int chunk = wave * 2 + j;
        const int row = chunk * 8 + sub;
        gload16(gsrc + (size_t)row * gstride + cg * 8, tile + chunk * 512);
    }
}

__device__ __forceinline__ bf16x8 frag(const short* tile, int row, int cg) {
    return *(const bf16x8*)&tile[row * 64 + ((cg ^ (row & 7)) << 3)];
}

// ---------------------------------------------------------------------------
// 64x64-tile MFMA GEMM mainloop, K=512, double-buffered global_load_lds.
// (16x16x32 MFMA; unchanged from round 5.)
// ---------------------------------------------------------------------------
__device__ __forceinline__ void gemm_mainloop_512(
    const short* __restrict__ Arow, const short* __restrict__ Brow,
    short* As, short* Bs, f32x4 acc[4], int t)
{
    const int wave = t >> 6, lane = t & 63, n16 = lane & 15, quad = lane >> 4;
    stage_tile(Arow, 512, As, t);
    stage_tile(Brow, 512, Bs, t);
    __syncthreads();
    for (int c = 0; c < 8; ++c) {
        const int cur = c & 1;
        if (c < 7) {
            stage_tile(Arow + (c + 1) * 64, 512, As + (1 - cur) * 4096, t);
            stage_tile(Brow + (c + 1) * 64, 512, Bs + (1 - cur) * 4096, t);
        }
        const short* as = As + cur * 4096;
        const short* bs = Bs + cur * 4096;
#pragma unroll
        for (int kh = 0; kh < 2; ++kh) {
            const bf16x8 a = frag(as, wave * 16 + n16, kh * 4 + quad);
#pragma unroll
            for (int nt = 0; nt < 4; ++nt) {
                const bf16x8 b = frag(bs, nt * 16 + n16, kh * 4 + quad);
                acc[nt] = __builtin_amdgcn_mfma_f32_16x16x32_bf16(a, b, acc[nt], 0, 0, 0);
            }
        }
        __syncthreads();
    }
}

// ---------------------------------------------------------------------------
// Prep: x->bf16; weight transposes via coalesced LDS tiles.
// ---------------------------------------------------------------------------
__global__ __launch_bounds__(256) void prep_kernel(
    const float* __restrict__ x,
    const float* __restrict__ Wq, const float* __restrict__ Wk,
    const float* __restrict__ Wv, const float* __restrict__ Wo,
    short* __restrict__ xb, short* __restrict__ Wqkvt, short* __restrict__ Wot)
{
    __shared__ short T[64 * 66];
    const int b = blockIdx.x, t = threadIdx.x;
    if (b < 1024) {
        const size_t idx = (size_t)b * 2048 + t * 8;
        const float4 a = *(const float4*)&x[idx];
        const float4 c = *(const float4*)&x[idx + 4];
        bf16x8 o;
        o[0] = f2bf(a.x); o[1] = f2bf(a.y); o[2] = f2bf(a.z); o[3] = f2bf(a.w);
        o[4] = f2bf(c.x); o[5] = f2bf(c.y); o[6] = f2bf(c.z); o[7] = f2bf(c.w);
        *(bf16x8*)&xb[idx] = o;
        return;
    }
    const int c4 = (t & 15) * 4, rsub = t >> 4;
    const int orow = t >> 2, oc16 = (t & 3) * 16;
    if (b < 1216) {
        const int jj = b - 1024, g = jj >> 3, kb = jj & 7;
        const int which = g >> 3, h = g & 7;
        const float* W = ((which == 0) ? Wq : (which == 1) ? Wk : Wv) + (size_t)h * 512 * 64;
#pragma unroll
        for (int p = 0; p < 4; ++p) {
            const int row = p * 16 + rsub;
            const float4 v = *(const float4*)&W[(size_t)(kb * 64 + row) * 64 + c4];
            T[(c4 + 0) * 66 + row] = f2bf(v.x);
            T[(c4 + 1) * 66 + row] = f2bf(v.y);
            T[(c4 + 2) * 66 + row] = f2bf(v.z);
            T[(c4 + 3) * 66 + row] = f2bf(v.w);
        }
        __syncthreads();
        short* O = &Wqkvt[((size_t)g * 64 + orow) * 512 + kb * 64];
        *(bf16x8*)&O[oc16]     = *(const bf16x8*)&T[orow * 66 + oc16];
        *(bf16x8*)&O[oc16 + 8] = *(const bf16x8*)&T[orow * 66 + oc16 + 8];
    } else {
        const int jj = b - 1216, h = jj >> 3, nb = jj & 7;
        const float* W = Wo + (size_t)h * 64 * 512;
#pragma unroll
        for (int p = 0; p < 4; ++p) {
            const int row = p * 16 + rsub;
            const float4 v = *(const float4*)&W[(size_t)row * 512 + nb * 64 + c4];
            T[(c4 + 0) * 66 + row] = f2bf(v.x);
            T[(c4 + 1) * 66 + row] = f2bf(v.y);
            T[(c4 + 2) * 66 + row] = f2bf(v.z);
            T[(c4 + 3) * 66 + row] = f2bf(v.w);
        }
        __syncthreads();
        short* O = &Wot[((size_t)nb * 64 + orow) * 512 + h * 64];
        *(bf16x8*)&O[oc16]     = *(const bf16x8*)&T[orow * 66 + oc16];
        *(bf16x8*)&O[oc16 + 8] = *(const bf16x8*)&T[orow * 66 + oc16 + 8];
    }
}

// ---------------------------------------------------------------------------
// QKV projection. Q pre-scaled by QSCALE; Q,K stored [h][s][64]; V stored
// transposed [h][d][s] via LDS bounce.
// ---------------------------------------------------------------------------
__global__ __launch_bounds__(256) void qkv_gemm_kernel(
    const short* __restrict__ xb, const short* __restrict__ Wqkvt,
    short* __restrict__ Qg, short* __restrict__ Kg, short* __restrict__ Vtg)
{
    __shared__ short smem[16384];
    short* As = smem;
    short* Bs = smem + 8192;
    const int sblk = blockIdx.x, g = blockIdx.y;
    const int which = g >> 3, h = g & 7;
    const int t = threadIdx.x;
    const int wave = t >> 6, lane = t & 63, n16 = lane & 15, quad = lane >> 4;

    f32x4 acc[4] = {{0,0,0,0},{0,0,0,0},{0,0,0,0},{0,0,0,0}};
    gemm_mainloop_512(xb + (size_t)sblk * 64 * 512, Wqkvt + (size_t)g * 64 * 512,
                      As, Bs, acc, t);

    if (which < 2) {
        const float scale = (which == 0) ? QSCALE : 1.0f;
        short* O = ((which == 0) ? Qg : Kg) + (size_t)h * S_LEN * 64;
#pragma unroll
        for (int nt = 0; nt < 4; ++nt)
#pragma unroll
            for (int r = 0; r < 4; ++r) {
                const int s = sblk * 64 + wave * 16 + quad * 4 + r;
                O[(size_t)s * 64 + nt * 16 + n16] = f2bf(acc[nt][r] * scale);
            }
    } else {
        __syncthreads();
        short* Tr = smem;
#pragma unroll
        for (int nt = 0; nt < 4; ++nt)
#pragma unroll
            for (int r = 0; r < 4; ++r)
                Tr[(nt * 16 + n16) * 66 + wave * 16 + quad * 4 + r] = f2bf(acc[nt][r]);
        __syncthreads();
        short* O = Vtg + (size_t)h * 64 * S_LEN + sblk * 64;
        const int r4 = t >> 2, c16 = (t & 3) * 16;
        *(bf16x8*)&O[(size_t)r4 * S_LEN + c16]     = *(const bf16x8*)&Tr[r4 * 66 + c16];
        *(bf16x8*)&O[(size_t)r4 * S_LEN + c16 + 8] = *(const bf16x8*)&Tr[r4 * 66 + c16 + 8];
    }
}

// ---------------------------------------------------------------------------
// Output projection: vals bf16 [4096][512] x Wot[n][c] -> out fp32.
// ---------------------------------------------------------------------------
__global__ __launch_bounds__(256) void out_gemm_kernel(
    const short* __restrict__ vals, const short* __restrict__ Wot, float* __restrict__ out)
{
    __shared__ short smem[16384];
    short* As = smem;
    short* Bs = smem + 8192;
    const int sblk = blockIdx.x, g = blockIdx.y;
    const int t = threadIdx.x;
    const int wave = t >> 6, lane = t & 63, n16 = lane & 15, quad = lane >> 4;

    f32x4 acc[4] = {{0,0,0,0},{0,0,0,0},{0,0,0,0},{0,0,0,0}};
    gemm_mainloop_512(vals + (size_t)sblk * 64 * 512, Wot + (size_t)g * 64 * 512,
                      As, Bs, acc, t);

#pragma unroll
    for (int nt = 0; nt < 4; ++nt)
#pragma unroll
        for (int r = 0; r < 4; ++r) {
            const int s = sblk * 64 + wave * 16 + quad * 4 + r;
            out[(size_t)s * 512 + g * 64 + nt * 16 + n16] = acc[nt][r];
        }
}

// ---------------------------------------------------------------------------
// Flash attention, causal, static-reference softmax (p = exp2(sc), exact by
// shift-invariance). 32x32x16 MFMA (2x FLOP per LDS byte vs 16x16x32):
//   Sc^T[key][q] = K x Q^T   A=K-frag (LDS), B=Q-frag (regs, invariant)
//   O^T[v][q]   += V^T x P   A=V^T-frag (LDS), B=P (wave-local LDS)
// C layout 32x32: col=lane&31 (= q, lane-local softmax),
// row=(reg&3)+8*(reg>>2)+4*(lane>>5). l = in-thread sum + shfl_xor(32).
// Block = 4 waves x 32 q = 128 q rows -> each K/V staging serves 2x the work.
// Split-k: 80 chunks (<=16 kb-steps) over 32 q-supers; grid 640 = 8h x 80;
// longest chunks dispatch first. Partials: Opart[slot][v=64][q=128] coalesced
// fp32 stores + Lpart[slot][q=128]; combine_norm sums <=4 slots.
// ---------------------------------------------------------------------------
__global__ __launch_bounds__(256, 3) void attn_kernel(
    const short* __restrict__ Qg, const short* __restrict__ Kg,
    const short* __restrict__ Vtg, float* __restrict__ Opart, float* __restrict__ Lpart)
{
    __shared__ short Ks[2][4096];
    __shared__ short Vs[2][4096];
    __shared__ short Ps[4 * 32 * 72];      // per-wave [q 32][key 64], stride 72

    const int id = blockIdx.x;
    const int h  = id & 7;
    const int c  = 79 - (id >> 3);         // reversed: longest chunks first
    int qs, j;
    if (c < 8)       { qs = c;                   j = 0; }
    else if (c < 24) { qs = 8 + ((c - 8) >> 1);  j = (c - 8) & 1; }
    else if (c < 48) { qs = 16 + (c - 24) / 3;   j = (c - 24) % 3; }
    else             { qs = 24 + ((c - 48) >> 2); j = (c - 48) & 3; }
    const int k0   = j * 16;
    const int kend = min(k0 + 16, 2 * qs + 2);

    const short* Kh  = Kg  + (size_t)h * S_LEN * 64;
    const short* Vth = Vtg + (size_t)h * 64 * S_LEN;

    const int t = threadIdx.x;
    const int wave = t >> 6, lane = t & 63, l31 = lane & 31, half = lane >> 5;
    const int qg = qs * 128 + wave * 32 + l31;   // this lane's global q

    // Q B-fragments, loop-invariant: B[k=d][n=q] = Q[qg][d]
    const short* Qr = Qg + (size_t)h * S_LEN * 64 + (size_t)qg * 64;
    bf16x8 bq[4];
#pragma unroll
    for (int kc = 0; kc < 4; ++kc)
        bq[kc] = *(const bf16x8*)&Qr[kc * 16 + half * 8];

    f32x16 oacc[2];
#pragma unroll
    for (int r = 0; r < 16; ++r) { oacc[0][r] = 0.f; oacc[1][r] = 0.f; }
    float lsum = 0.f;
    short* Pw = Ps + wave * (32 * 72);

    stage_tile(Kh + (size_t)k0 * 64 * 64, 64, Ks[0], t);
    stage_tile(Vth + k0 * 64, S_LEN, Vs[0], t);
    __syncthreads();

    for (int kb = k0; kb < kend; ++kb) {
        const int cur = (kb - k0) & 1;
        if (kb + 1 < kend) {               // async prefetch into other buffer
            stage_tile(Kh + (size_t)(kb + 1) * 64 * 64, 64, Ks[1 - cur], t);
            stage_tile(Vth + (kb + 1) * 64, S_LEN, Vs[1 - cur], t);
        }

        // Sc^T = K x Q^T  (2 key-tiles x 4 d-chunks)
        f32x16 sc[2];
#pragma unroll
        for (int r = 0; r < 16; ++r) { sc[0][r] = 0.f; sc[1][r] = 0.f; }
#pragma unroll
        for (int kc = 0; kc < 4; ++kc) {
            const bf16x8 a0 = frag(Ks[cur], l31,      kc * 2 + half);
            const bf16x8 a1 = frag(Ks[cur], 32 + l31, kc * 2 + half);
            sc[0] = __builtin_amdgcn_mfma_f32_32x32x16_bf16(a0, bq[kc], sc[0], 0, 0, 0);
            sc[1] = __builtin_amdgcn_mfma_f32_32x32x16_bf16(a1, bq[kc], sc[1], 0, 0, 0);
        }

        // causal mask: only tiles that straddle the diagonal
        if (kb * 64 + 63 > qg) {
#pragma unroll
            for (int mt = 0; mt < 2; ++mt)
#pragma unroll
                for (int r = 0; r < 16; ++r) {
                    const int key = kb * 64 + mt * 32 + (r & 3) + 8 * (r >> 2) + 4 * half;
                    if (key > qg) sc[mt][r] = -1e30f;
                }
        }

        // p = exp2(sc); in-thread l partial; packed bf16 to wave-local Ps
#pragma unroll
        for (int mt = 0; mt < 2; ++mt)
#pragma unroll
            for (int g2 = 0; g2 < 4; ++g2) {
                const float p0 = __builtin_amdgcn_exp2f(sc[mt][4 * g2 + 0]);
                const float p1 = __builtin_amdgcn_exp2f(sc[mt][4 * g2 + 1]);
                const float p2 = __builtin_amdgcn_exp2f(sc[mt][4 * g2 + 2]);
                const float p3 = __builtin_amdgcn_exp2f(sc[mt][4 * g2 + 3]);
                lsum += (p0 + p1) + (p2 + p3);
                int2 w; w.x = pk2(p0, p1); w.y = pk2(p2, p3);
                *(int2*)&Pw[l31 * 72 + mt * 32 + g2 * 8 + half * 4] = w;
            }
        __builtin_amdgcn_wave_barrier();   // Ps writes stay above PV reads

        // O^T += V^T x P  (2 v-tiles x 4 key-chunks; B = Ps row, wave-local)
#pragma unroll
        for (int kc = 0; kc < 4; ++kc) {
            const bf16x8 bp = *(const bf16x8*)&Pw[l31 * 72 + kc * 16 + half * 8];
            const bf16x8 a0 = frag(Vs[cur], l31,      kc * 2 + half);
            const bf16x8 a1 = frag(Vs[cur], 32 + l31, kc * 2 + half);
            oacc[0] = __builtin_amdgcn_mfma_f32_32x32x16_bf16(a0, bp, oacc[0], 0, 0, 0);
            oacc[1] = __builtin_amdgcn_mfma_f32_32x32x16_bf16(a1, bp, oacc[1], 0, 0, 0);
        }
        __builtin_amdgcn_wave_barrier();
        __syncthreads();                   // buffer swap + prefetch drain
    }

    // l: combine the two half-wave partials (each lane then has full l[qg])
    lsum += __shfl_xor(lsum, 32);

    // coalesced fp32 partial stores
    float* tileO = Opart + (size_t)(h * 80 + c) * (64 * 128);
    float* tileL = Lpart + (h * 80 + c) * 128;
    if (half == 0) tileL[wave * 32 + l31] = lsum;
#pragma unroll
    for (int mt = 0; mt < 2; ++mt)
#pragma unroll
        for (int r = 0; r < 16; ++r) {
            const int v = mt * 32 + (r & 3) + 8 * (r >> 2) + 4 * half;
            tileO[(v << 7) + wave * 32 + l31] = oacc[mt][r];
        }
}

// ---------------------------------------------------------------------------
// Combine partials + normalize + transpose -> vals[s][h*64+v] bf16.
// One block per (h, q-super of 128): sum <=4 slot tiles [v 64][q 128],
// divide by summed l[q], bf16-pack into LDS [q][v] (stride 66), write rows.
// ---------------------------------------------------------------------------
__global__ __launch_bounds__(256) void combine_norm_kernel(
    const float* __restrict__ Opart, const float* __restrict__ Lpart,
    short* __restrict__ vals)
{
    __shared__ short T[128 * 66];
    const int id = blockIdx.x;
    const int h = id & 7, qs = id >> 3;
    int c0, nj;
    if (qs < 8)       { c0 = qs;                nj = 1; }
    else if (qs < 16) { c0 = 8 + 2 * (qs - 8);  nj = 2; }
    else if (qs < 24) { c0 = 24 + 3 * (qs - 16); nj = 3; }
    else              { c0 = 48 + 4 * (qs - 24); nj = 4; }
    const int base = h * 80 + c0;

    const int t = threadIdx.x;
    const int q0 = (t & 31) * 4;
    const int vr = t >> 5;

    f32x4 L = {0, 0, 0, 0};
    for (int j = 0; j < nj; ++j)
        L += *(const f32x4*)&Lpart[(base + j) * 128 + q0];
    const f32x4 inv = {1.f / L[0], 1.f / L[1], 1.f / L[2], 1.f / L[3]};

#pragma unroll
    for (int pass = 0; pass < 8; ++pass) {
        const int v = vr + pass * 8;
        f32x4 s = {0, 0, 0, 0};
        for (int j = 0; j < nj; ++j)
            s += *(const f32x4*)&Opart[(size_t)(base + j) * 8192 + (v << 7) + q0];
        T[(q0 + 0) * 66 + v] = f2bf(s[0] * inv[0]);
        T[(q0 + 1) * 66 + v] = f2bf(s[1] * inv[1]);
        T[(q0 + 2) * 66 + v] = f2bf(s[2] * inv[2]);
        T[(q0 + 3) * 66 + v] = f2bf(s[3] * inv[3]);
    }
    __syncthreads();
    const int q = t >> 1, vh = (t & 1) * 32;
    const size_t row = (size_t)(qs * 128 + q) * 512 + h * 64 + vh;
#pragma unroll
    for (int u = 0; u < 4; ++u)
        *(bf16x8*)&vals[row + u * 8] = *(const bf16x8*)&T[q * 66 + vh + u * 8];
}

// ---------------------------------------------------------------------------
// Workspace: shorts (xb | Wqkvt | Wot | Qg | Kg | Vtg | vals) ~22 MB, then
// fp32 Opart 640x8192 (20 MB) + Lpart 640x128  ~= 43 MB.
// ---------------------------------------------------------------------------
extern "C" void kernel_launch(void* const* d_in, const int* in_sizes, int n_in,
                              void* d_out, int out_size, void* d_ws, size_t ws_size,
                              hipStream_t stream)
{
    const float* x  = (const float*)d_in[0];
    const float* Wq = (const float*)d_in[1];
    const float* Wk = (const float*)d_in[2];
    const float* Wv = (const float*)d_in[3];
    const float* Wo = (const float*)d_in[4];
    float* out = (float*)d_out;

    short* xb    = (short*)d_ws;
    short* Wqkvt = xb + 2097152;
    short* Wot   = Wqkvt + 786432;
    short* Qg    = Wot + 262144;
    short* Kg    = Qg + 2097152;
    short* Vtg   = Kg + 2097152;
    short* vals  = Vtg + 2097152;
    float* Opart = (float*)(vals + 2097152);
    float* Lpart = Opart + (size_t)640 * 8192;

    prep_kernel<<<1280, 256, 0, stream>>>(x, Wq, Wk, Wv, Wo, xb, Wqkvt, Wot);
    qkv_gemm_kernel<<<dim3(64, 24), 256, 0, stream>>>(xb, Wqkvt, Qg, Kg, Vtg);
    attn_kernel<<<640, 256, 0, stream>>>(Qg, Kg, Vtg, Opart, Lpart);
    combine_norm_kernel<<<256, 256, 0, stream>>>(Opart, Lpart, vals);
    out_gemm_kernel<<<dim3(64, 8), 256, 0, stream>>>(vals, Wot, out);
}

// Round 7
// 134.407 us; speedup vs baseline: 1.0234x; 1.0234x over previous
//
#include <hip/hip_runtime.h>
#include <hip/hip_bf16.h>
#include <math.h>

#define S_LEN 4096
#define NH    8

typedef __attribute__((ext_vector_type(8))) short bf16x8;
typedef __attribute__((ext_vector_type(4))) short bf16x4;
typedef __attribute__((ext_vector_type(4))) float f32x4;
typedef __attribute__((ext_vector_type(16))) float f32x16;

#define QSCALE 0.18033688011112042f   // 0.125 * log2(e): scores land in exp2 domain

// s_waitcnt imm (gfx9 encoding): vmcnt[3:0], expcnt=7 (dc), lgkmcnt=15 (dc)
#define WAIT_VM4 0x0F74
#define WAIT_VM0 0x0F70

// fp32 -> bf16 round-to-nearest-even (scalar)
__device__ __forceinline__ short f2bf(float f) {
    union { float f; unsigned u; } v; v.f = f;
    unsigned r = v.u + 0x7fffu + ((v.u >> 16) & 1u);
    return (short)(r >> 16);
}

// packed 2x fp32 -> bf16 (v_cvt_pk_bf16_f32 on gfx950)
__device__ __forceinline__ int pk2(float a, float b) {
    __hip_bfloat162 t = __float22bfloat162_rn(make_float2(a, b));
    union { __hip_bfloat162 h; int i; } u; u.h = t;
    return u.i;
}

// async 16B global->LDS; HW writes lane i's 16B to ldsbase + i*16
__device__ __forceinline__ void gload16(const void* g, void* l) {
    __builtin_amdgcn_global_load_lds(
        (const __attribute__((address_space(1))) unsigned*)g,
        (__attribute__((address_space(3))) unsigned*)l, 16, 0, 0);
}

// ---------------------------------------------------------------------------
// Stage a 64x64 bf16 tile into an 8KB LDS tile with XOR-swizzled 16B column
// groups: phys(row, cg) = row*128B + ((cg ^ (row&7)) * 16B). Swizzle applied
// on the GLOBAL source address so wave-uniform-base global_load_lds lands
// data where frag() expects.  2 loads per wave per tile.
// ---------------------------------------------------------------------------
__device__ __forceinline__ void stage_tile(const short* gsrc, size_t gstride,
                                           short* tile, int t)
{
    const int wave = t >> 6, lane = t & 63;
    const int sub = lane >> 3;
    const int cg  = (lane & 7) ^ sub;
#pragma unroll
    for (int j = 0; j < 2; ++j) {
        const int chunk = wave * 2 + j;
        const int row = chunk * 8 + sub;
        gload16(gsrc + (size_t)row * gstride + cg * 8, tile + chunk * 512);
    }
}

__device__ __forceinline__ bf16x8 frag(const short* tile, int row, int cg) {
    return *(const bf16x8*)&tile[row * 64 + ((cg ^ (row & 7)) << 3)];
}

// ---------------------------------------------------------------------------
// 64x64-tile MFMA GEMM mainloop, K=512, double-buffered global_load_lds with
// RAW-BARRIER pipeline (no vmcnt(0) drain): per step
//   barrier_A (all waves done reading buf^1) -> prefetch t+1 into buf^1 ->
//   s_waitcnt vmcnt(4) (t's loads done, t+1's in flight) -> barrier_B ->
//   compute on buf.
// ---------------------------------------------------------------------------
__device__ __forceinline__ void gemm_mainloop_512(
    const short* __restrict__ Arow, const short* __restrict__ Brow,
    short* As, short* Bs, f32x4 acc[4], int t)
{
    const int wave = t >> 6, lane = t & 63, n16 = lane & 15, quad = lane >> 4;
    stage_tile(Arow, 512, As, t);
    stage_tile(Brow, 512, Bs, t);
    for (int c = 0; c < 8; ++c) {
        const int cur = c & 1;
        __builtin_amdgcn_s_barrier();                  // A
        if (c < 7) {
            stage_tile(Arow + (c + 1) * 64, 512, As + (1 - cur) * 4096, t);
            stage_tile(Brow + (c + 1) * 64, 512, Bs + (1 - cur) * 4096, t);
            __builtin_amdgcn_s_waitcnt(WAIT_VM4);
        } else {
            __builtin_amdgcn_s_waitcnt(WAIT_VM0);
        }
        __builtin_amdgcn_s_barrier();                  // B
        const short* as = As + cur * 4096;
        const short* bs = Bs + cur * 4096;
#pragma unroll
        for (int kh = 0; kh < 2; ++kh) {
            const bf16x8 a = frag(as, wave * 16 + n16, kh * 4 + quad);
#pragma unroll
            for (int nt = 0; nt < 4; ++nt) {
                const bf16x8 b = frag(bs, nt * 16 + n16, kh * 4 + quad);
                acc[nt] = __builtin_amdgcn_mfma_f32_16x16x32_bf16(a, b, acc[nt], 0, 0, 0);
            }
        }
    }
}

// ---------------------------------------------------------------------------
// Prep: x->bf16; weight transposes via coalesced LDS tiles.
// ---------------------------------------------------------------------------
__global__ __launch_bounds__(256) void prep_kernel(
    const float* __restrict__ x,
    const float* __restrict__ Wq, const float* __restrict__ Wk,
    const float* __restrict__ Wv, const float* __restrict__ Wo,
    short* __restrict__ xb, short* __restrict__ Wqkvt, short* __restrict__ Wot)
{
    __shared__ short T[64 * 66];
    const int b = blockIdx.x, t = threadIdx.x;
    if (b < 1024) {
        const size_t idx = (size_t)b * 2048 + t * 8;
        const float4 a = *(const float4*)&x[idx];
        const float4 c = *(const float4*)&x[idx + 4];
        bf16x8 o;
        o[0] = f2bf(a.x); o[1] = f2bf(a.y); o[2] = f2bf(a.z); o[3] = f2bf(a.w);
        o[4] = f2bf(c.x); o[5] = f2bf(c.y); o[6] = f2bf(c.z); o[7] = f2bf(c.w);
        *(bf16x8*)&xb[idx] = o;
        return;
    }
    const int c4 = (t & 15) * 4, rsub = t >> 4;
    const int orow = t >> 2, oc16 = (t & 3) * 16;
    if (b < 1216) {
        const int jj = b - 1024, g = jj >> 3, kb = jj & 7;
        const int which = g >> 3, h = g & 7;
        const float* W = ((which == 0) ? Wq : (which == 1) ? Wk : Wv) + (size_t)h * 512 * 64;
#pragma unroll
        for (int p = 0; p < 4; ++p) {
            const int row = p * 16 + rsub;
            const float4 v = *(const float4*)&W[(size_t)(kb * 64 + row) * 64 + c4];
            T[(c4 + 0) * 66 + row] = f2bf(v.x);
            T[(c4 + 1) * 66 + row] = f2bf(v.y);
            T[(c4 + 2) * 66 + row] = f2bf(v.z);
            T[(c4 + 3) * 66 + row] = f2bf(v.w);
        }
        __syncthreads();
        short* O = &Wqkvt[((size_t)g * 64 + orow) * 512 + kb * 64];
        *(bf16x8*)&O[oc16]     = *(const bf16x8*)&T[orow * 66 + oc16];
        *(bf16x8*)&O[oc16 + 8] = *(const bf16x8*)&T[orow * 66 + oc16 + 8];
    } else {
        const int jj = b - 1216, h = jj >> 3, nb = jj & 7;
        const float* W = Wo + (size_t)h * 64 * 512;
#pragma unroll
        for (int p = 0; p < 4; ++p) {
            const int row = p * 16 + rsub;
            const float4 v = *(const float4*)&W[(size_t)row * 512 + nb * 64 + c4];
            T[(c4 + 0) * 66 + row] = f2bf(v.x);
            T[(c4 + 1) * 66 + row] = f2bf(v.y);
            T[(c4 + 2) * 66 + row] = f2bf(v.z);
            T[(c4 + 3) * 66 + row] = f2bf(v.w);
        }
        __syncthreads();
        short* O = &Wot[((size_t)nb * 64 + orow) * 512 + h * 64];
        *(bf16x8*)&O[oc16]     = *(const bf16x8*)&T[orow * 66 + oc16];
        *(bf16x8*)&O[oc16 + 8] = *(const bf16x8*)&T[orow * 66 + oc16 + 8];
    }
}

// ---------------------------------------------------------------------------
// QKV projection. Q pre-scaled by QSCALE; Q,K stored [h][s][64]; V stored
// transposed [h][d][s] via LDS bounce.
// ---------------------------------------------------------------------------
__global__ __launch_bounds__(256) void qkv_gemm_kernel(
    const short* __restrict__ xb, const short* __restrict__ Wqkvt,
    short* __restrict__ Qg, short* __restrict__ Kg, short* __restrict__ Vtg)
{
    __shared__ short smem[16384];
    short* As = smem;
    short* Bs = smem + 8192;
    const int sblk = blockIdx.x, g = blockIdx.y;
    const int which = g >> 3, h = g & 7;
    const int t = threadIdx.x;
    const int wave = t >> 6, lane = t & 63, n16 = lane & 15, quad = lane >> 4;

    f32x4 acc[4] = {{0,0,0,0},{0,0,0,0},{0,0,0,0},{0,0,0,0}};
    gemm_mainloop_512(xb + (size_t)sblk * 64 * 512, Wqkvt + (size_t)g * 64 * 512,
                      As, Bs, acc, t);

    if (which < 2) {
        const float scale = (which == 0) ? QSCALE : 1.0f;
        short* O = ((which == 0) ? Qg : Kg) + (size_t)h * S_LEN * 64;
#pragma unroll
        for (int nt = 0; nt < 4; ++nt)
#pragma unroll
            for (int r = 0; r < 4; ++r) {
                const int s = sblk * 64 + wave * 16 + quad * 4 + r;
                O[(size_t)s * 64 + nt * 16 + n16] = f2bf(acc[nt][r] * scale);
            }
    } else {
        __syncthreads();                   // all waves done with smem
        short* Tr = smem;
#pragma unroll
        for (int nt = 0; nt < 4; ++nt)
#pragma unroll
            for (int r = 0; r < 4; ++r)
                Tr[(nt * 16 + n16) * 66 + wave * 16 + quad * 4 + r] = f2bf(acc[nt][r]);
        __syncthreads();
        short* O = Vtg + (size_t)h * 64 * S_LEN + sblk * 64;
        const int r4 = t >> 2, c16 = (t & 3) * 16;
        *(bf16x8*)&O[(size_t)r4 * S_LEN + c16]     = *(const bf16x8*)&Tr[r4 * 66 + c16];
        *(bf16x8*)&O[(size_t)r4 * S_LEN + c16 + 8] = *(const bf16x8*)&Tr[r4 * 66 + c16 + 8];
    }
}

// ---------------------------------------------------------------------------
// Output projection: vals bf16 [4096][512] x Wot[n][c] -> out fp32.
// ---------------------------------------------------------------------------
__global__ __launch_bounds__(256) void out_gemm_kernel(
    const short* __restrict__ vals, const short* __restrict__ Wot, float* __restrict__ out)
{
    __shared__ short smem[16384];
    short* As = smem;
    short* Bs = smem + 8192;
    const int sblk = blockIdx.x, g = blockIdx.y;
    const int t = threadIdx.x;
    const int wave = t >> 6, lane = t & 63, n16 = lane & 15, quad = lane >> 4;

    f32x4 acc[4] = {{0,0,0,0},{0,0,0,0},{0,0,0,0},{0,0,0,0}};
    gemm_mainloop_512(vals + (size_t)sblk * 64 * 512, Wot + (size_t)g * 64 * 512,
                      As, Bs, acc, t);

#pragma unroll
    for (int nt = 0; nt < 4; ++nt)
#pragma unroll
        for (int r = 0; r < 4; ++r) {
            const int s = sblk * 64 + wave * 16 + quad * 4 + r;
            out[(size_t)s * 512 + g * 64 + nt * 16 + n16] = acc[nt][r];
        }
}

// ---------------------------------------------------------------------------
// Flash attention, causal, static-reference softmax (p = exp2(sc), exact by
// shift-invariance). 32x32x16 MFMA, raw-barrier pipelined staging (see
// gemm_mainloop comment). Per step:
//   Sc^T[key][q] = K x Q^T   (C init from invariant zero regs)
//   O^T[v][q]   += V^T x P ; l via ones-A MFMA (complete per lane, no shfl)
// Block = 4 waves x 32 q = 128 q. Split-k: 80 chunks (<=16 steps) over 32
// q-supers; grid 640 = 8h x 80; longest chunks first. Partials: coalesced
// fp32 stores Opart[slot][v 64][q 128] + Lpart[slot][q 128].
// ---------------------------------------------------------------------------
__global__ __launch_bounds__(256, 3) void attn_kernel(
    const short* __restrict__ Qg, const short* __restrict__ Kg,
    const short* __restrict__ Vtg, float* __restrict__ Opart, float* __restrict__ Lpart)
{
    __shared__ short Ks[2][4096];
    __shared__ short Vs[2][4096];
    __shared__ short Ps[4 * 32 * 72];      // per-wave [q 32][key 64], stride 72

    const int id = blockIdx.x;
    const int h  = id & 7;
    const int c  = 79 - (id >> 3);         // reversed: longest chunks first
    int qs, j;
    if (c < 8)       { qs = c;                   j = 0; }
    else if (c < 24) { qs = 8 + ((c - 8) >> 1);  j = (c - 8) & 1; }
    else if (c < 48) { qs = 16 + (c - 24) / 3;   j = (c - 24) % 3; }
    else             { qs = 24 + ((c - 48) >> 2); j = (c - 48) & 3; }
    const int k0   = j * 16;
    const int kend = min(k0 + 16, 2 * qs + 2);

    const short* Kh  = Kg  + (size_t)h * S_LEN * 64;
    const short* Vth = Vtg + (size_t)h * 64 * S_LEN;

    const int t = threadIdx.x;
    const int wave = t >> 6, lane = t & 63, l31 = lane & 31, half = lane >> 5;
    const int qg = qs * 128 + wave * 32 + l31;   // this lane's global q

    // Q B-fragments, loop-invariant: B[k=d][n=q] = Q[qg][d]
    const short* Qr = Qg + (size_t)h * S_LEN * 64 + (size_t)qg * 64;
    bf16x8 bq[4];
#pragma unroll
    for (int kc = 0; kc < 4; ++kc)
        bq[kc] = *(const bf16x8*)&Qr[kc * 16 + half * 8];

    // all-ones A fragment (bf16 1.0) for l accumulation on the matrix pipe
    bf16x8 ones;
#pragma unroll
    for (int i = 0; i < 8; ++i) ones[i] = (short)0x3F80;

    // invariant zero C operand for score MFMAs
    f32x16 z16;
#pragma unroll
    for (int r = 0; r < 16; ++r) z16[r] = 0.f;

    f32x16 oacc[2], lacc;
#pragma unroll
    for (int r = 0; r < 16; ++r) { oacc[0][r] = 0.f; oacc[1][r] = 0.f; lacc[r] = 0.f; }
    short* Pw = Ps + wave * (32 * 72);

    stage_tile(Kh + (size_t)k0 * 64 * 64, 64, Ks[0], t);
    stage_tile(Vth + k0 * 64, S_LEN, Vs[0], t);

    for (int kb = k0; kb < kend; ++kb) {
        const int cur = (kb - k0) & 1;
        __builtin_amdgcn_s_barrier();                  // A: buf^1 free to overwrite
        if (kb + 1 < kend) {
            stage_tile(Kh + (size_t)(kb + 1) * 64 * 64, 64, Ks[1 - cur], t);
            stage_tile(Vth + (kb + 1) * 64, S_LEN, Vs[1 - cur], t);
            __builtin_amdgcn_s_waitcnt(WAIT_VM4);      // kb's 4 loads done
        } else {
            __builtin_amdgcn_s_waitcnt(WAIT_VM0);
        }
        __builtin_amdgcn_s_barrier();                  // B: buf cur ready for all

        // Sc^T = K x Q^T  (kc=0 seeds from invariant zero regs)
        f32x16 sc0, sc1;
        {
            const bf16x8 a0 = frag(Ks[cur], l31,      half);
            const bf16x8 a1 = frag(Ks[cur], 32 + l31, half);
            sc0 = __builtin_amdgcn_mfma_f32_32x32x16_bf16(a0, bq[0], z16, 0, 0, 0);
            sc1 = __builtin_amdgcn_mfma_f32_32x32x16_bf16(a1, bq[0], z16, 0, 0, 0);
        }
#pragma unroll
        for (int kc = 1; kc < 4; ++kc) {
            const bf16x8 a0 = frag(Ks[cur], l31,      kc * 2 + half);
            const bf16x8 a1 = frag(Ks[cur], 32 + l31, kc * 2 + half);
            sc0 = __builtin_amdgcn_mfma_f32_32x32x16_bf16(a0, bq[kc], sc0, 0, 0, 0);
            sc1 = __builtin_amdgcn_mfma_f32_32x32x16_bf16(a1, bq[kc], sc1, 0, 0, 0);
        }

        // causal mask: only tiles that straddle the diagonal
        if (kb * 64 + 63 > qg) {
#pragma unroll
            for (int r = 0; r < 16; ++r) {
                const int keyb = kb * 64 + (r & 3) + 8 * (r >> 2) + 4 * half;
                if (keyb > qg)      sc0[r] = -1e30f;
                if (keyb + 32 > qg) sc1[r] = -1e30f;
            }
        }

        // p = exp2(sc); packed bf16 to wave-local Ps
#pragma unroll
        for (int g2 = 0; g2 < 4; ++g2) {
            int2 w;
            w.x = pk2(__builtin_amdgcn_exp2f(sc0[4 * g2 + 0]),
                      __builtin_amdgcn_exp2f(sc0[4 * g2 + 1]));
            w.y = pk2(__builtin_amdgcn_exp2f(sc0[4 * g2 + 2]),
                      __builtin_amdgcn_exp2f(sc0[4 * g2 + 3]));
            *(int2*)&Pw[l31 * 72 + g2 * 8 + half * 4] = w;
            int2 w2;
            w2.x = pk2(__builtin_amdgcn_exp2f(sc1[4 * g2 + 0]),
                       __builtin_amdgcn_exp2f(sc1[4 * g2 + 1]));
            w2.y = pk2(__builtin_amdgcn_exp2f(sc1[4 * g2 + 2]),
                       __builtin_amdgcn_exp2f(sc1[4 * g2 + 3]));
            *(int2*)&Pw[l31 * 72 + 32 + g2 * 8 + half * 4] = w2;
        }
        __builtin_amdgcn_wave_barrier();   // Ps writes stay above PV reads

        // O^T += V^T x P ; l += ones x P   (all B = wave-local Ps rows)
#pragma unroll
        for (int kc = 0; kc < 4; ++kc) {
            const bf16x8 bp = *(const bf16x8*)&Pw[l31 * 72 + kc * 16 + half * 8];
            const bf16x8 a0 = frag(Vs[cur], l31,      kc * 2 + half);
            const bf16x8 a1 = frag(Vs[cur], 32 + l31, kc * 2 + half);
            oacc[0] = __builtin_amdgcn_mfma_f32_32x32x16_bf16(a0, bp, oacc[0], 0, 0, 0);
            oacc[1] = __builtin_amdgcn_mfma_f32_32x32x16_bf16(a1, bp, oacc[1], 0, 0, 0);
            lacc    = __builtin_amdgcn_mfma_f32_32x32x16_bf16(ones, bp, lacc, 0, 0, 0);
        }
        __builtin_amdgcn_wave_barrier();
    }

    // coalesced fp32 partial stores (lacc rows are all identical = l[q])
    float* tileO = Opart + (size_t)(h * 80 + c) * (64 * 128);
    float* tileL = Lpart + (h * 80 + c) * 128;
    if (half == 0) tileL[wave * 32 + l31] = lacc[0];
#pragma unroll
    for (int mt = 0; mt < 2; ++mt)
#pragma unroll
        for (int r = 0; r < 16; ++r) {
            const int v = mt * 32 + (r & 3) + 8 * (r >> 2) + 4 * half;
            tileO[(v << 7) + wave * 32 + l31] = (mt ? oacc[1][r] : oacc[0][r]);
        }
}

// ---------------------------------------------------------------------------
// Combine partials + normalize + transpose -> vals[s][h*64+v] bf16.
// One block per (h, q-super of 128): sum <=4 slot tiles [v 64][q 128],
// divide by summed l[q], bf16-pack into LDS [q][v] (stride 66), write rows.
// ---------------------------------------------------------------------------
__global__ __launch_bounds__(256) void combine_norm_kernel(
    const float* __restrict__ Opart, const float* __restrict__ Lpart,
    short* __restrict__ vals)
{
    __shared__ short T[128 * 66];
    const int id = blockIdx.x;
    const int h = id & 7, qs = id >> 3;
    int c0, nj;
    if (qs < 8)       { c0 = qs;                 nj = 1; }
    else if (qs < 16) { c0 = 8 + 2 * (qs - 8);   nj = 2; }
    else if (qs < 24) { c0 = 24 + 3 * (qs - 16); nj = 3; }
    else              { c0 = 48 + 4 * (qs - 24); nj = 4; }
    const int base = h * 80 + c0;

    const int t = threadIdx.x;
    const int q0 = (t & 31) * 4;
    const int vr = t >> 5;

    f32x4 L = {0, 0, 0, 0};
    for (int j = 0; j < nj; ++j)
        L += *(const f32x4*)&Lpart[(base + j) * 128 + q0];
    const f32x4 inv = {1.f / L[0], 1.f / L[1], 1.f / L[2], 1.f / L[3]};

#pragma unroll
    for (int pass = 0; pass < 8; ++pass) {
        const int v = vr + pass * 8;
        f32x4 s = {0, 0, 0, 0};
        for (int j = 0; j < nj; ++j)
            s += *(const f32x4*)&Opart[(size_t)(base + j) * 8192 + (v << 7) + q0];
        T[(q0 + 0) * 66 + v] = f2bf(s[0] * inv[0]);
        T[(q0 + 1) * 66 + v] = f2bf(s[1] * inv[1]);
        T[(q0 + 2) * 66 + v] = f2bf(s[2] * inv[2]);
        T[(q0 + 3) * 66 + v] = f2bf(s[3] * inv[3]);
    }
    __syncthreads();
    const int q = t >> 1, vh = (t & 1) * 32;
    const size_t row = (size_t)(qs * 128 + q) * 512 + h * 64 + vh;
#pragma unroll
    for (int u = 0; u < 4; ++u)
        *(bf16x8*)&vals[row + u * 8] = *(const bf16x8*)&T[q * 66 + vh + u * 8];
}

// ---------------------------------------------------------------------------
// Workspace: shorts (xb | Wqkvt | Wot | Qg | Kg | Vtg | vals) ~22 MB, then
// fp32 Opart 640x8192 (20 MB) + Lpart 640x128  ~= 43 MB.
// ---------------------------------------------------------------------------
extern "C" void kernel_launch(void* const* d_in, const int* in_sizes, int n_in,
                              void* d_out, int out_size, void* d_ws, size_t ws_size,
                              hipStream_t stream)
{
    const float* x  = (const float*)d_in[0];
    const float* Wq = (const float*)d_in[1];
    const float* Wk = (const float*)d_in[2];
    const float* Wv = (const float*)d_in[3];
    const float* Wo = (const float*)d_in[4];
    float* out = (float*)d_out;

    short* xb    = (short*)d_ws;
    short* Wqkvt = xb + 2097152;
    short* Wot   = Wqkvt + 786432;
    short* Qg    = Wot + 262144;
    short* Kg    = Qg + 2097152;
    short* Vtg   = Kg + 2097152;
    short* vals  = Vtg + 2097152;
    float* Opart = (float*)(vals + 2097152);
    float* Lpart = Opart + (size_t)640 * 8192;

    prep_kernel<<<1280, 256, 0, stream>>>(x, Wq, Wk, Wv, Wo, xb, Wqkvt, Wot);
    qkv_gemm_kernel<<<dim3(64, 24), 256, 0, stream>>>(xb, Wqkvt, Qg, Kg, Vtg);
    attn_kernel<<<640, 256, 0, stream>>>(Qg, Kg, Vtg, Opart, Lpart);
    combine_norm_kernel<<<256, 256, 0, stream>>>(Opart, Lpart, vals);
    out_gemm_kernel<<<dim3(64, 8), 256, 0, stream>>>(vals, Wot, out);
}